// Round 8
// baseline (166.240 us; speedup 1.0000x reference)
//
#include <hip/hip_runtime.h>

// Problem constants
#define BATCH 16
#define CH 64          // EMBEDDING_DIM
#define HW 4096        // 64*64
#define NPIX 65536     // BATCH*HW
#define KCODES 512
#define DDIM 64
#define NELEM 4194304  // NPIX*CH

// d_out layout (float32): [z_q_st: NELEM][loss: 1][ppl: 1][indices: NPIX]
#define OUT_LOSS 4194304
#define OUT_PPL  4194305
#define OUT_IDX  4194306

// bf16 gap-error: rms ~4e-5 => 2.2e-4 is ~5.5 sigma; covers np fp32 quantization (7.6e-6)
#define MARGIN 2.2e-4f

typedef short bf16x8 __attribute__((ext_vector_type(8)));
typedef float f32x4  __attribute__((ext_vector_type(4)));

__device__ __forceinline__ float rnd(float s) {   // block fp-contract (numpy-exact squares)
    asm volatile("" : "+v"(s));
    return s;
}
__device__ __forceinline__ short f2bf(float f) {  // RNE fp32->bf16
    unsigned u = __builtin_bit_cast(unsigned, f);
    unsigned r = (u + 0x7fffu + ((u >> 16) & 1u)) >> 16;
    return (short)r;
}

// -------------------- prep: e2 + fragment-ordered bf16 codebook + coalesced fp32 transpose ---
// Bh packing: entry = tn*128 + chunk*64 + lane, lane=(q<<4)|i:
//   code = tn*16+i, k = chunk*32 + q*8 + j (j=0..7), 16B/entry.  (layout HW-verified R4)
// P2 packing (for refine): P4[(kk*16+c4)*64 + lane] = emb[lane*8+kk][c4*4..+3]
//   -> refine's per-lane float4 load is a fully coalesced 1KB wave instruction.
__global__ void k_prep(const float* __restrict__ emb, float* __restrict__ e2,
                       bf16x8* __restrict__ Bh, float4* __restrict__ P4) {
    int gid = blockIdx.x * 256 + threadIdx.x;
    if (gid < 4096) {
        int tn = gid >> 7, rem = gid & 127;
        int chunk = (rem >> 6) & 1, q = (rem >> 4) & 3, i = rem & 15;
        int code = tn * 16 + i;
        const float* src = emb + code * DDIM + chunk * 32 + q * 8;
        bf16x8 h;
        #pragma unroll
        for (int j = 0; j < 8; ++j) h[j] = f2bf(src[j]);
        Bh[gid] = h;
    } else if (gid < 4608) {
        int k = gid - 4096;
        const float* row = emb + k * DDIM;
        float r[8];
        #pragma unroll
        for (int j = 0; j < 8; ++j) { float v = row[j]; r[j] = rnd(v * v); }
        #pragma unroll
        for (int m = 1; m < 8; ++m)
            #pragma unroll
            for (int j = 0; j < 8; ++j) { float v = row[8 * m + j]; r[j] += rnd(v * v); }
        e2[k] = ((r[0] + r[1]) + (r[2] + r[3])) + ((r[4] + r[5]) + (r[6] + r[7]));
    } else if (gid < 12800) {
        int pid = gid - 4608;            // 8192 entries
        int kk = pid >> 10, c4 = (pid >> 6) & 15, lane = pid & 63;
        int code = lane * 8 + kk;
        P4[pid] = *(const float4*)(emb + code * DDIM + c4 * 4);
    }
}

// -------------------- fused distance/argmin + epilogue kernel --------------------
// 128 px/block, 4 waves x 32 px (2 M-tiles/wave). Grid 512 -> 2 blocks/CU.
// Codebook staged in LDS (32KB half at a time): NO global loads in the N-loop.
#define ROWW 40   // u32 stride per px row (16B-aligned frags, modest bank spread)
__global__ __launch_bounds__(256, 2) void k_dist(
        const float* __restrict__ z_e, const float* __restrict__ emb,
        const bf16x8* __restrict__ Bh, const float* __restrict__ e2g,
        int* __restrict__ idx, int* __restrict__ glist, int* __restrict__ nflag,
        int* __restrict__ counts, float* __restrict__ slots,
        float* __restrict__ out) {
    __shared__ unsigned AhU[128 * ROWW];   // 20 KB
    __shared__ bf16x8 Bs[2048];            // 32 KB: half the codebook, fragment order
    __shared__ float e2s[512];
    __shared__ int   hist[512];
    __shared__ int   flist[128];
    __shared__ int   fcnt, fbase;

    int t = threadIdx.x;
    int pxbase = blockIdx.x * 128;
    int batch = pxbase >> 12;
    int p0 = pxbase & 4095;
    const float* zb = z_e + (size_t)batch * (CH * HW) + p0;

    hist[t] = 0; hist[t + 256] = 0;
    e2s[t] = e2g[t]; e2s[t + 256] = e2g[t + 256];
    if (t == 0) fcnt = 0;

    // stage A: 128px x 64ch -> bf16, 2 ch packed per u32. Coalesced loads.
    #pragma unroll
    for (int it = 0; it < 16; ++it) {
        int i = it * 256 + t;            // 0..4095 channel-pair x px
        int cp = i >> 7;                 // channel pair 0..31
        int pp = i & 127;                // px
        float v0 = zb[(2 * cp) * HW + pp];
        float v1 = zb[(2 * cp + 1) * HW + pp];
        AhU[pp * ROWW + cp] = (unsigned)(unsigned short)f2bf(v0)
                            | ((unsigned)(unsigned short)f2bf(v1) << 16);
    }
    __syncthreads();

    int w = t >> 6, lane = t & 63, col = lane & 15, quad = lane >> 4;

    // A fragments: wave w owns px m = w*32 + mt*16 + col; k = chunk*32 + quad*8 + j
    const short* Ahs = (const short*)AhU;
    bf16x8 a[2][2];
    #pragma unroll
    for (int mt = 0; mt < 2; ++mt) {
        int m = w * 32 + mt * 16 + col;
        a[mt][0] = *(const bf16x8*)(Ahs + m * (2 * ROWW) + quad * 8);
        a[mt][1] = *(const bf16x8*)(Ahs + m * (2 * ROWW) + 32 + quad * 8);
    }

    float m1[2][4], m2[2][4];
    int   i1[2][4];
    #pragma unroll
    for (int mt = 0; mt < 2; ++mt)
        #pragma unroll
        for (int r = 0; r < 4; ++r) { m1[mt][r] = 1e30f; m2[mt][r] = 1e30f; i1[mt][r] = 0; }

    // N loop over 2 codebook halves, each staged into LDS
    for (int h = 0; h < 2; ++h) {
        __syncthreads();   // previous half's reads complete before overwrite
        #pragma unroll
        for (int it = 0; it < 8; ++it) {
            int e = it * 256 + t;
            Bs[e] = Bh[h * 2048 + e];    // coalesced 1KB/wave -> ds_write_b128
        }
        __syncthreads();
        #pragma unroll 4
        for (int tn16 = 0; tn16 < 16; ++tn16) {
            int tn = h * 16 + tn16;
            bf16x8 c0 = Bs[tn16 * 128 + lane];
            bf16x8 c1 = Bs[tn16 * 128 + 64 + lane];
            float e2v = e2s[tn * 16 + col];
            int n = tn * 16 + col;
            #pragma unroll
            for (int mt = 0; mt < 2; ++mt) {
                f32x4 acc = {0.f, 0.f, 0.f, 0.f};
                acc = __builtin_amdgcn_mfma_f32_16x16x32_bf16(a[mt][0], c0, acc, 0, 0, 0);
                acc = __builtin_amdgcn_mfma_f32_16x16x32_bf16(a[mt][1], c1, acc, 0, 0, 0);
                #pragma unroll
                for (int r = 0; r < 4; ++r) {
                    float d = fmaf(-2.0f, acc[r], e2v);
                    if (d < m1[mt][r])      { m2[mt][r] = m1[mt][r]; m1[mt][r] = d; i1[mt][r] = n; }
                    else if (d < m2[mt][r]) { m2[mt][r] = d; }
                }
            }
        }
    }

    // merge the 16 cols (xor butterfly -> every lane holds result for px quad*4+r)
    #pragma unroll
    for (int off = 1; off < 16; off <<= 1) {
        #pragma unroll
        for (int mt = 0; mt < 2; ++mt)
            #pragma unroll
            for (int r = 0; r < 4; ++r) {
                float om1 = __shfl_xor(m1[mt][r], off);
                float om2 = __shfl_xor(m2[mt][r], off);
                int   oi  = __shfl_xor(i1[mt][r], off);
                if (om1 < m1[mt][r] || (om1 == m1[mt][r] && oi < i1[mt][r])) {
                    m2[mt][r] = fminf(m1[mt][r], om2);
                    m1[mt][r] = om1;
                    i1[mt][r] = oi;
                } else {
                    m2[mt][r] = fminf(m2[mt][r], om1);
                }
            }
    }

    // per-pixel outputs: idx, out-idx, LDS histogram + LDS flag list (no global atomics)
    if (col == 0) {
        #pragma unroll
        for (int mt = 0; mt < 2; ++mt)
            #pragma unroll
            for (int r = 0; r < 4; ++r) {
                int g = pxbase + w * 32 + mt * 16 + quad * 4 + r;
                idx[g] = i1[mt][r];
                out[OUT_IDX + g] = (float)i1[mt][r];
                atomicAdd(&hist[i1[mt][r]], 1);
                if (m2[mt][r] - m1[mt][r] < MARGIN) {
                    int pos = atomicAdd(&fcnt, 1);   // LDS atomic
                    flist[pos] = g;
                }
            }
    }

    // fused epilogue: z_q_st for this wave's 32 px (z_e is L1-hot), + loss partial
    int q4 = lane & 3;
    float lsum = 0.0f;
    #pragma unroll
    for (int mt = 0; mt < 2; ++mt) {
        int bidx[4];
        #pragma unroll
        for (int j = 0; j < 4; ++j) bidx[j] = __shfl(i1[mt][j], q4 << 4);
        const float* zw = zb + w * 32 + mt * 16;
        float* ow = out + (size_t)batch * (CH * HW) + p0 + w * 32 + mt * 16;
        #pragma unroll
        for (int it = 0; it < 4; ++it) {
            int c = it * 16 + (lane >> 2);
            float4 ze = *(const float4*)(zw + c * HW + q4 * 4);
            float d0 = emb[bidx[0] * DDIM + c] - ze.x;
            float d1 = emb[bidx[1] * DDIM + c] - ze.y;
            float d2 = emb[bidx[2] * DDIM + c] - ze.z;
            float d3 = emb[bidx[3] * DDIM + c] - ze.w;
            float4 o = {ze.x + d0, ze.y + d1, ze.z + d2, ze.w + d3};
            *(float4*)(ow + c * HW + q4 * 4) = o;
            lsum = lsum + d0 * d0 + d1 * d1 + d2 * d2 + d3 * d3;
        }
    }
    #pragma unroll
    for (int off = 32; off; off >>= 1) lsum += __shfl_down(lsum, off);
    if (lane == 0) atomicAdd(&slots[((blockIdx.x * 4 + w) & 63) * 16], lsum);

    // flush histogram + flag list (one returning atomic per block)
    __syncthreads();
    int v0 = hist[t];       if (v0) atomicAdd(&counts[t], v0);
    int v1 = hist[t + 256]; if (v1) atomicAdd(&counts[t + 256], v1);
    if (t == 0) fbase = atomicAdd(nflag, fcnt);
    __syncthreads();
    if (t < fcnt) glist[fbase + t] = flist[t];
}

// -------------------- refine: one wave per flagged pixel (numpy-fp32-exact) --------
// __launch_bounds__(256) is LOAD-BEARING: without it VGPRs cap at 64 and xv[64]
// spills to scratch (R5: 90 MB HBM writes, 235 us). Codebook reads go through the
// P4 lane-coalesced transpose (R7's per-lane row reads were 64 lines/instr).
__global__ __launch_bounds__(256) void k_refine(
        const float* __restrict__ z_e, const float* __restrict__ emb,
        const float* __restrict__ e2, const float4* __restrict__ P4,
        const int* __restrict__ glist, const int* __restrict__ nflag,
        int* __restrict__ idx, int* __restrict__ counts,
        float* __restrict__ slots, float* __restrict__ out) {
    __shared__ float xs[4][64];
    int w = threadIdx.x >> 6, lane = threadIdx.x & 63;
    int wid = blockIdx.x * 4 + w;
    int nw = gridDim.x * 4;
    int n = nflag[0];

    for (int i = wid; i < n; i += nw) {
        int g = glist[i];
        int b = g >> 12, p = g & 4095;
        const float* xp = z_e + (size_t)b * (CH * HW) + p;

        float xc = xp[lane * HW];        // lane c loads channel c
        xs[w][lane] = xc;
        __threadfence_block();           // wave-lockstep LDS visibility

        float xv[64];
        #pragma unroll
        for (int c4 = 0; c4 < 16; ++c4) {
            float4 tmp = *(const float4*)&xs[w][c4 * 4];
            xv[c4 * 4 + 0] = tmp.x; xv[c4 * 4 + 1] = tmp.y;
            xv[c4 * 4 + 2] = tmp.z; xv[c4 * 4 + 3] = tmp.w;
        }
        // numpy pairwise sum of squares (8 accumulators + tree)
        float r[8];
        #pragma unroll
        for (int j = 0; j < 8; ++j) r[j] = rnd(xv[j] * xv[j]);
        #pragma unroll
        for (int mm = 1; mm < 8; ++mm)
            #pragma unroll
            for (int j = 0; j < 8; ++j) r[j] += rnd(xv[8 * mm + j] * xv[8 * mm + j]);
        float x2 = ((r[0] + r[1]) + (r[2] + r[3])) + ((r[4] + r[5]) + (r[6] + r[7]));

        float bestd = INFINITY;
        int besti = 1 << 30;
        for (int kk = 0; kk < 8; ++kk) {
            int k = lane * 8 + kk;       // this lane's candidate code
            double d0 = 0.0, d1 = 0.0, d2 = 0.0, d3 = 0.0;
            #pragma unroll
            for (int c4 = 0; c4 < 16; ++c4) {
                float4 ev = P4[(kk * 16 + c4) * 64 + lane];  // coalesced 1KB/instr
                d0 = fma((double)xv[c4 * 4 + 0], (double)ev.x, d0);
                d1 = fma((double)xv[c4 * 4 + 1], (double)ev.y, d1);
                d2 = fma((double)xv[c4 * 4 + 2], (double)ev.z, d2);
                d3 = fma((double)xv[c4 * 4 + 3], (double)ev.w, d3);
            }
            float dotf = (float)((d0 + d1) + (d2 + d3));  // ~= sgemm dot
            float tt = x2 + e2[k];                        // np fp32 add
            float d = tt - 2.0f * dotf;                   // np fp32 sub
            if (d < bestd) { bestd = d; besti = k; }      // ascending k: first wins
        }
        #pragma unroll
        for (int off = 32; off; off >>= 1) {
            float od = __shfl_down(bestd, off);
            int   oi = __shfl_down(besti, off);
            if (od < bestd || (od == bestd && oi < besti)) { bestd = od; besti = oi; }
        }
        besti = __shfl(besti, 0);

        int old = idx[g];
        if (besti != old) {
            // patch z_q_st row (lane c = channel c), loss delta, counts, index
            float qn = emb[besti * DDIM + lane];
            float qo = emb[old * DDIM + lane];
            float dn = qn - xc, dold = qo - xc;
            out[(size_t)b * (CH * HW) + (size_t)lane * HW + p] = xc + dn;
            float delta = dn * dn - dold * dold;
            #pragma unroll
            for (int off = 32; off; off >>= 1) delta += __shfl_down(delta, off);
            if (lane == 0) {
                atomicAdd(&slots[(wid & 63) * 16], delta);
                atomicAdd(&counts[old], -1);
                atomicAdd(&counts[besti], 1);
                idx[g] = besti;
                out[OUT_IDX + g] = (float)besti;
            }
        }
    }
}

// -------------------- final scalars: loss, perplexity --------------------
__global__ void k_final(const int* __restrict__ counts,
                        const float* __restrict__ slots,
                        float* __restrict__ out) {
    int t = threadIdx.x;  // 512 threads, 1 block
    float cnt = (float)counts[t];
    float pb = cnt * (1.0f / 65536.0f);
    float term = pb * logf(pb + 1e-10f);
    #pragma unroll
    for (int off = 32; off; off >>= 1) term += __shfl_down(term, off);
    __shared__ float ls[8];
    __shared__ float lsum;
    int lane = t & 63, w = t >> 6;
    if (lane == 0) ls[w] = term;
    if (w == 0) {                               // wave 0 reduces the 64 loss slots
        float s2 = slots[lane * 16];
        #pragma unroll
        for (int off = 32; off; off >>= 1) s2 += __shfl_down(s2, off);
        if (lane == 0) lsum = s2;
    }
    __syncthreads();
    if (t == 0) {
        float s = 0.0f;
        #pragma unroll
        for (int i = 0; i < 8; ++i) s += ls[i];
        out[OUT_PPL]  = expf(-s);
        out[OUT_LOSS] = 0.25f * (lsum / (float)NELEM);
    }
}

extern "C" void kernel_launch(void* const* d_in, const int* in_sizes, int n_in,
                              void* d_out, int out_size, void* d_ws, size_t ws_size,
                              hipStream_t stream) {
    const float* z_e = (const float*)d_in[0];
    const float* emb = (const float*)d_in[1];
    float* out = (float*)d_out;
    char* ws = (char*)d_ws;

    // ws layout
    int*    idx    = (int*)(ws);              // 65536 ints   [0, 262144)
    int*    glist  = (int*)(ws + 262144);     // 65536 ints   [262144, 524288)
    float*  e2     = (float*)(ws + 524288);   // 512 floats   [524288, 526336)
    int*    nflag  = (int*)(ws + 526336);     // 1 int (+pad) [526336, 526400)
    int*    counts = (int*)(ws + 526400);     // 512 ints     [526400, 528448)
    float*  slots  = (float*)(ws + 528448);   // 64 x 16 floats [528448, 532544)
    bf16x8* Bh     = (bf16x8*)(ws + 532544);  // 4096 x 16 B = 64 KB
    float4* P4     = (float4*)(ws + 598080);  // 8192 x 16 B = 128 KB [598080, 729152)

    // zero nflag + counts + slots (ws is poisoned 0xAA before every timed launch)
    hipMemsetAsync(ws + 526336, 0, 532544 - 526336, stream);

    k_prep<<<50, 256, 0, stream>>>(emb, e2, Bh, P4);
    k_dist<<<NPIX / 128, 256, 0, stream>>>(z_e, emb, Bh, e2, idx, glist, nflag, counts, slots, out);
    k_refine<<<1024, 256, 0, stream>>>(z_e, emb, e2, P4, glist, nflag, idx, counts, slots, out);
    k_final<<<1, 512, 0, stream>>>(counts, slots, out);
}

// Round 9
// 150.111 us; speedup vs baseline: 1.1074x; 1.1074x over previous
//
#include <hip/hip_runtime.h>

// Problem constants
#define BATCH 16
#define CH 64          // EMBEDDING_DIM
#define HW 4096        // 64*64
#define NPIX 65536     // BATCH*HW
#define KCODES 512
#define DDIM 64
#define NELEM 4194304  // NPIX*CH

// d_out layout (float32): [z_q_st: NELEM][loss: 1][ppl: 1][indices: NPIX]
#define OUT_LOSS 4194304
#define OUT_PPL  4194305
#define OUT_IDX  4194306

// bf16 gap-error: rms ~4e-5 => 2.2e-4 is ~5.5 sigma; covers np fp32 quantization (7.6e-6)
#define MARGIN 2.2e-4f

typedef short bf16x8 __attribute__((ext_vector_type(8)));
typedef float f32x4  __attribute__((ext_vector_type(4)));

__device__ __forceinline__ float rnd(float s) {   // block fp-contract (numpy-exact squares)
    asm volatile("" : "+v"(s));
    return s;
}
__device__ __forceinline__ short f2bf(float f) {  // RNE fp32->bf16
    unsigned u = __builtin_bit_cast(unsigned, f);
    unsigned r = (u + 0x7fffu + ((u >> 16) & 1u)) >> 16;
    return (short)r;
}

// -------------------- prep: e2 + fragment-ordered bf16 codebook + coalesced fp32 transpose ---
// Bh packing: entry = tn*128 + chunk*64 + lane, lane=(q<<4)|i:
//   code = tn*16+i, k = chunk*32 + q*8 + j (j=0..7), 16B/entry.  (layout HW-verified R4)
// P4 packing (for refine): P4[(kk*16+c4)*64 + lane] = emb[lane*8+kk][c4*4..+3]
__global__ void k_prep(const float* __restrict__ emb, float* __restrict__ e2,
                       bf16x8* __restrict__ Bh, float4* __restrict__ P4) {
    int gid = blockIdx.x * 256 + threadIdx.x;
    if (gid < 4096) {
        int tn = gid >> 7, rem = gid & 127;
        int chunk = (rem >> 6) & 1, q = (rem >> 4) & 3, i = rem & 15;
        int code = tn * 16 + i;
        const float* src = emb + code * DDIM + chunk * 32 + q * 8;
        bf16x8 h;
        #pragma unroll
        for (int j = 0; j < 8; ++j) h[j] = f2bf(src[j]);
        Bh[gid] = h;
    } else if (gid < 4608) {
        int k = gid - 4096;
        const float* row = emb + k * DDIM;
        float r[8];
        #pragma unroll
        for (int j = 0; j < 8; ++j) { float v = row[j]; r[j] = rnd(v * v); }
        #pragma unroll
        for (int m = 1; m < 8; ++m)
            #pragma unroll
            for (int j = 0; j < 8; ++j) { float v = row[8 * m + j]; r[j] += rnd(v * v); }
        e2[k] = ((r[0] + r[1]) + (r[2] + r[3])) + ((r[4] + r[5]) + (r[6] + r[7]));
    } else if (gid < 12800) {
        int pid = gid - 4608;            // 8192 entries
        int kk = pid >> 10, c4 = (pid >> 6) & 15, lane = pid & 63;
        int code = lane * 8 + kk;
        P4[pid] = *(const float4*)(emb + code * DDIM + c4 * 4);
    }
}

// -------------------- fused distance/argmin + epilogue kernel --------------------
// 64 px/block, 4 waves x 16 px. Grid 1024 -> 4 blocks/CU (31 KB LDS).
// bf16 codebook staged in LDS 16KB quarters: NO global loads in the N-loop.
#define ROWW 40   // u32 stride per px row (16B-aligned frags, modest bank spread)
__global__ __launch_bounds__(256, 4) void k_dist(
        const float* __restrict__ z_e, const float* __restrict__ emb,
        const bf16x8* __restrict__ Bh, const float* __restrict__ e2g,
        int* __restrict__ idx, int* __restrict__ glist, int* __restrict__ nflag,
        int* __restrict__ counts, float* __restrict__ slots,
        float* __restrict__ out) {
    __shared__ unsigned AhU[64 * ROWW];    // 10 KB
    __shared__ bf16x8 Bs[1024];            // 16 KB: quarter codebook, fragment order
    __shared__ float e2s[512];
    __shared__ int   hist[512];
    __shared__ int   flist[64];
    __shared__ int   fcnt, fbase;

    int t = threadIdx.x;
    int pxbase = blockIdx.x * 64;
    int batch = pxbase >> 12;
    int p0 = pxbase & 4095;
    const float* zb = z_e + (size_t)batch * (CH * HW) + p0;

    hist[t] = 0; hist[t + 256] = 0;
    e2s[t] = e2g[t]; e2s[t + 256] = e2g[t + 256];
    if (t == 0) fcnt = 0;

    // stage A: 64px x 64ch -> bf16, 2 ch packed per u32. Coalesced loads.
    #pragma unroll
    for (int it = 0; it < 8; ++it) {
        int i = it * 256 + t;            // 0..2047 channel-pair x px
        int cp = i >> 6;                 // channel pair 0..31
        int pp = i & 63;                 // px
        float v0 = zb[(2 * cp) * HW + pp];
        float v1 = zb[(2 * cp + 1) * HW + pp];
        AhU[pp * ROWW + cp] = (unsigned)(unsigned short)f2bf(v0)
                            | ((unsigned)(unsigned short)f2bf(v1) << 16);
    }
    __syncthreads();

    int w = t >> 6, lane = t & 63, col = lane & 15, quad = lane >> 4;

    // A fragments: wave w owns px m = w*16 + col; k = chunk*32 + quad*8 + j
    const short* Ahs = (const short*)AhU;
    int m = w * 16 + col;
    bf16x8 a0 = *(const bf16x8*)(Ahs + m * (2 * ROWW) + quad * 8);
    bf16x8 a1 = *(const bf16x8*)(Ahs + m * (2 * ROWW) + 32 + quad * 8);

    float m1[4], m2[4];
    int   i1[4];
    #pragma unroll
    for (int r = 0; r < 4; ++r) { m1[r] = 1e30f; m2[r] = 1e30f; i1[r] = 0; }

    // N loop over 4 codebook quarters, each staged into LDS
    for (int qtr = 0; qtr < 4; ++qtr) {
        __syncthreads();   // previous quarter's reads complete before overwrite
        #pragma unroll
        for (int it = 0; it < 4; ++it) Bs[it * 256 + t] = Bh[qtr * 1024 + it * 256 + t];
        __syncthreads();
        #pragma unroll
        for (int tn8 = 0; tn8 < 8; ++tn8) {
            int tn = qtr * 8 + tn8;
            bf16x8 c0 = Bs[tn8 * 128 + lane];
            bf16x8 c1 = Bs[tn8 * 128 + 64 + lane];
            float e2v = e2s[tn * 16 + col];
            int n = tn * 16 + col;
            f32x4 acc = {0.f, 0.f, 0.f, 0.f};
            acc = __builtin_amdgcn_mfma_f32_16x16x32_bf16(a0, c0, acc, 0, 0, 0);
            acc = __builtin_amdgcn_mfma_f32_16x16x32_bf16(a1, c1, acc, 0, 0, 0);
            #pragma unroll
            for (int r = 0; r < 4; ++r) {
                float d = fmaf(-2.0f, acc[r], e2v);
                if (d < m1[r])      { m2[r] = m1[r]; m1[r] = d; i1[r] = n; }
                else if (d < m2[r]) { m2[r] = d; }
            }
        }
    }

    // merge the 16 cols (xor butterfly -> every lane holds result for px quad*4+r)
    #pragma unroll
    for (int off = 1; off < 16; off <<= 1) {
        #pragma unroll
        for (int r = 0; r < 4; ++r) {
            float om1 = __shfl_xor(m1[r], off);
            float om2 = __shfl_xor(m2[r], off);
            int   oi  = __shfl_xor(i1[r], off);
            if (om1 < m1[r] || (om1 == m1[r] && oi < i1[r])) {
                m2[r] = fminf(m1[r], om2);
                m1[r] = om1;
                i1[r] = oi;
            } else {
                m2[r] = fminf(m2[r], om1);
            }
        }
    }

    // per-pixel outputs: idx, out-idx, LDS histogram + LDS flag list (no global atomics)
    if (col == 0) {
        #pragma unroll
        for (int r = 0; r < 4; ++r) {
            int g = pxbase + w * 16 + quad * 4 + r;
            idx[g] = i1[r];
            out[OUT_IDX + g] = (float)i1[r];
            atomicAdd(&hist[i1[r]], 1);
            if (m2[r] - m1[r] < MARGIN) {
                int pos = atomicAdd(&fcnt, 1);   // LDS atomic
                flist[pos] = g;
            }
        }
    }

    // fused epilogue: z_q_st for this wave's 16 px (z_e is L1-hot), + loss partial
    int q4 = lane & 3;
    int bidx[4];
    #pragma unroll
    for (int j = 0; j < 4; ++j) bidx[j] = __shfl(i1[j], q4 << 4);  // best for px q4*4+j
    const float* zw = zb + w * 16;
    float* ow = out + (size_t)batch * (CH * HW) + p0 + w * 16;
    float lsum = 0.0f;
    #pragma unroll
    for (int it = 0; it < 4; ++it) {
        int c = it * 16 + (lane >> 2);
        float4 ze = *(const float4*)(zw + c * HW + q4 * 4);
        float d0 = emb[bidx[0] * DDIM + c] - ze.x;
        float d1 = emb[bidx[1] * DDIM + c] - ze.y;
        float d2 = emb[bidx[2] * DDIM + c] - ze.z;
        float d3 = emb[bidx[3] * DDIM + c] - ze.w;
        float4 o = {ze.x + d0, ze.y + d1, ze.z + d2, ze.w + d3};
        *(float4*)(ow + c * HW + q4 * 4) = o;
        lsum = lsum + d0 * d0 + d1 * d1 + d2 * d2 + d3 * d3;
    }
    #pragma unroll
    for (int off = 32; off; off >>= 1) lsum += __shfl_down(lsum, off);
    if (lane == 0) atomicAdd(&slots[((blockIdx.x * 4 + w) & 63) * 16], lsum);

    // flush histogram + flag list (one returning atomic per block)
    __syncthreads();
    int v0 = hist[t];       if (v0) atomicAdd(&counts[t], v0);
    int v1 = hist[t + 256]; if (v1) atomicAdd(&counts[t + 256], v1);
    if (t == 0) fbase = atomicAdd(nflag, fcnt);
    __syncthreads();
    if (t < fcnt) glist[fbase + t] = flist[t];
}

// -------------------- refine: LDS-staged codebook, numpy-fp32-exact re-argmin ------
// R8 lesson: per-pixel global codebook loads serialize at ~400-900 cyc each under
// VGPR pressure -> 50+ us/pixel. Here the fp32 codebook is staged in LDS quarters
// (32 KB) and each wave's flagged-pixel x-vectors live in LDS: the dot loop is
// pure ds_read_b128 + fp64 FMA. 256 blocks x 4 waves; wave wid takes flags
// wid + f*1024 (balanced); all block waves run the same quarter/sync schedule.
__global__ __launch_bounds__(256) void k_refine(
        const float* __restrict__ z_e, const float* __restrict__ emb,
        const float* __restrict__ e2, const float4* __restrict__ P4,
        const int* __restrict__ glist, const int* __restrict__ nflag,
        int* __restrict__ idx, int* __restrict__ counts,
        float* __restrict__ slots, float* __restrict__ out) {
    __shared__ float4 Ps[2048];      // 32 KB: quarter of transposed codebook
    __shared__ float  xs[32][64];    // 8 KB: 8 flag slots per wave

    int t = threadIdx.x;
    int w = t >> 6, lane = t & 63;
    int wid = blockIdx.x * 4 + w;
    int n = nflag[0];
    if (blockIdx.x * 4 >= n) return;           // block-uniform early exit

    // per-lane e2 for codes lane*8..+7 (coalesced float4 pair)
    float4 ea = ((const float4*)e2)[lane * 2];
    float4 eb = ((const float4*)e2)[lane * 2 + 1];
    float e2v[8] = {ea.x, ea.y, ea.z, ea.w, eb.x, eb.y, eb.z, eb.w};

    for (int s = 0; s * 8192 + blockIdx.x * 4 < n; ++s) {   // block-uniform
        // gather this wave's flags (<=8), stage x-vectors into LDS
        int gidx[8];
        int nf = 0;
        #pragma unroll
        for (int f = 0; f < 8; ++f) {
            int j = s * 8192 + f * 1024 + wid;
            if (j < n) {
                int g = glist[j];                 // wave-uniform scalar load
                gidx[nf] = g;
                int b = g >> 12, p = g & 4095;
                xs[w * 8 + nf][lane] = z_e[(size_t)b * (CH * HW) + (size_t)lane * HW + p];
                ++nf;
            }
        }
        __threadfence_block();

        // numpy pairwise ||x||^2 per flag (broadcast LDS reads)
        float x2f[8];
        for (int f = 0; f < nf; ++f) {
            const float* xr = xs[w * 8 + f];
            float r[8];
            #pragma unroll
            for (int j = 0; j < 8; ++j) { float v = xr[j]; r[j] = rnd(v * v); }
            #pragma unroll
            for (int mm = 1; mm < 8; ++mm)
                #pragma unroll
                for (int j = 0; j < 8; ++j) { float v = xr[8 * mm + j]; r[j] += rnd(v * v); }
            x2f[f] = ((r[0] + r[1]) + (r[2] + r[3])) + ((r[4] + r[5]) + (r[6] + r[7]));
        }

        float bestd[8];
        int   besti[8];
        #pragma unroll
        for (int f = 0; f < 8; ++f) { bestd[f] = INFINITY; besti[f] = 1 << 30; }

        // 4 codebook quarters staged in LDS; lane's codes = lane*8 + (qtr*2+kk2)
        for (int qtr = 0; qtr < 4; ++qtr) {
            __syncthreads();
            #pragma unroll
            for (int it = 0; it < 8; ++it) Ps[it * 256 + t] = P4[qtr * 2048 + it * 256 + t];
            __syncthreads();
            for (int f = 0; f < nf; ++f) {
                const float* xr = xs[w * 8 + f];
                #pragma unroll
                for (int kk2 = 0; kk2 < 2; ++kk2) {
                    double d0 = 0.0, d1 = 0.0, d2 = 0.0, d3 = 0.0;
                    #pragma unroll
                    for (int c4 = 0; c4 < 16; ++c4) {
                        float4 xq = *(const float4*)&xr[c4 * 4];         // broadcast
                        float4 ev = Ps[(kk2 * 16 + c4) * 64 + lane];     // per-lane
                        d0 = fma((double)xq.x, (double)ev.x, d0);
                        d1 = fma((double)xq.y, (double)ev.y, d1);
                        d2 = fma((double)xq.z, (double)ev.z, d2);
                        d3 = fma((double)xq.w, (double)ev.w, d3);
                    }
                    int kk = qtr * 2 + kk2;
                    float dotf = (float)((d0 + d1) + (d2 + d3));  // ~= sgemm dot
                    float tt = x2f[f] + e2v[kk];                  // np fp32 add
                    float d = tt - 2.0f * dotf;                   // np fp32 sub
                    if (d < bestd[f]) { bestd[f] = d; besti[f] = lane * 8 + kk; }
                }
            }
        }

        // reduce per flag (tie -> smaller index = np first occurrence) and patch
        for (int f = 0; f < nf; ++f) {
            float bd = bestd[f];
            int   bi = besti[f];
            #pragma unroll
            for (int off = 32; off; off >>= 1) {
                float od = __shfl_down(bd, off);
                int   oi = __shfl_down(bi, off);
                if (od < bd || (od == bd && oi < bi)) { bd = od; bi = oi; }
            }
            bi = __shfl(bi, 0);
            int g = gidx[f];
            int old = idx[g];
            if (bi != old) {
                int b = g >> 12, p = g & 4095;
                float xc = xs[w * 8 + f][lane];
                float qn = emb[bi * DDIM + lane];
                float qo = emb[old * DDIM + lane];
                float dn = qn - xc, dold = qo - xc;
                out[(size_t)b * (CH * HW) + (size_t)lane * HW + p] = xc + dn;
                float delta = dn * dn - dold * dold;
                #pragma unroll
                for (int off = 32; off; off >>= 1) delta += __shfl_down(delta, off);
                if (lane == 0) {
                    atomicAdd(&slots[(wid & 63) * 16], delta);
                    atomicAdd(&counts[old], -1);
                    atomicAdd(&counts[bi], 1);
                    idx[g] = bi;
                    out[OUT_IDX + g] = (float)bi;
                }
            }
        }
    }
}

// -------------------- final scalars: loss, perplexity --------------------
__global__ void k_final(const int* __restrict__ counts,
                        const float* __restrict__ slots,
                        float* __restrict__ out) {
    int t = threadIdx.x;  // 512 threads, 1 block
    float cnt = (float)counts[t];
    float pb = cnt * (1.0f / 65536.0f);
    float term = pb * logf(pb + 1e-10f);
    #pragma unroll
    for (int off = 32; off; off >>= 1) term += __shfl_down(term, off);
    __shared__ float ls[8];
    __shared__ float lsum;
    int lane = t & 63, w = t >> 6;
    if (lane == 0) ls[w] = term;
    if (w == 0) {                               // wave 0 reduces the 64 loss slots
        float s2 = slots[lane * 16];
        #pragma unroll
        for (int off = 32; off; off >>= 1) s2 += __shfl_down(s2, off);
        if (lane == 0) lsum = s2;
    }
    __syncthreads();
    if (t == 0) {
        float s = 0.0f;
        #pragma unroll
        for (int i = 0; i < 8; ++i) s += ls[i];
        out[OUT_PPL]  = expf(-s);
        out[OUT_LOSS] = 0.25f * (lsum / (float)NELEM);
    }
}

extern "C" void kernel_launch(void* const* d_in, const int* in_sizes, int n_in,
                              void* d_out, int out_size, void* d_ws, size_t ws_size,
                              hipStream_t stream) {
    const float* z_e = (const float*)d_in[0];
    const float* emb = (const float*)d_in[1];
    float* out = (float*)d_out;
    char* ws = (char*)d_ws;

    // ws layout
    int*    idx    = (int*)(ws);              // 65536 ints   [0, 262144)
    int*    glist  = (int*)(ws + 262144);     // 65536 ints   [262144, 524288)
    float*  e2     = (float*)(ws + 524288);   // 512 floats   [524288, 526336)
    int*    nflag  = (int*)(ws + 526336);     // 1 int (+pad) [526336, 526400)
    int*    counts = (int*)(ws + 526400);     // 512 ints     [526400, 528448)
    float*  slots  = (float*)(ws + 528448);   // 64 x 16 floats [528448, 532544)
    bf16x8* Bh     = (bf16x8*)(ws + 532544);  // 4096 x 16 B = 64 KB
    float4* P4     = (float4*)(ws + 598080);  // 8192 x 16 B = 128 KB [598080, 729152)

    // zero nflag + counts + slots (ws is poisoned 0xAA before every timed launch)
    hipMemsetAsync(ws + 526336, 0, 532544 - 526336, stream);

    k_prep<<<50, 256, 0, stream>>>(emb, e2, Bh, P4);
    k_dist<<<NPIX / 64, 256, 0, stream>>>(z_e, emb, Bh, e2, idx, glist, nflag, counts, slots, out);
    k_refine<<<256, 256, 0, stream>>>(z_e, emb, e2, P4, glist, nflag, idx, counts, slots, out);
    k_final<<<1, 512, 0, stream>>>(counts, slots, out);
}

// Round 10
// 148.597 us; speedup vs baseline: 1.1187x; 1.0102x over previous
//
#include <hip/hip_runtime.h>

// Problem constants
#define BATCH 16
#define CH 64          // EMBEDDING_DIM
#define HW 4096        // 64*64
#define NPIX 65536     // BATCH*HW
#define KCODES 512
#define DDIM 64
#define NELEM 4194304  // NPIX*CH

// d_out layout (float32): [z_q_st: NELEM][loss: 1][ppl: 1][indices: NPIX]
#define OUT_LOSS 4194304
#define OUT_PPL  4194305
#define OUT_IDX  4194306

// bf16 gap-error: rms ~4e-5 => 2.2e-4 is ~5.5 sigma; covers np fp32 quantization (7.6e-6)
#define MARGIN 2.2e-4f

typedef short bf16x8 __attribute__((ext_vector_type(8)));
typedef float f32x4  __attribute__((ext_vector_type(4)));

__device__ __forceinline__ float rnd(float s) {   // block fp-contract (numpy-exact squares)
    asm volatile("" : "+v"(s));
    return s;
}
__device__ __forceinline__ short f2bf(float f) {  // RNE fp32->bf16
    unsigned u = __builtin_bit_cast(unsigned, f);
    unsigned r = (u + 0x7fffu + ((u >> 16) & 1u)) >> 16;
    return (short)r;
}

// -------------------- prep: e2 + fragment-ordered bf16 codebook + coalesced fp32 transpose ---
// Bh packing: entry = tn*128 + chunk*64 + lane, lane=(q<<4)|i:
//   code = tn*16+i, k = chunk*32 + q*8 + j (j=0..7), 16B/entry.  (layout HW-verified R4)
// P4 packing (for refine): P4[(kk*16+c4)*64 + lane] = emb[lane*8+kk][c4*4..+3]
__global__ void k_prep(const float* __restrict__ emb, float* __restrict__ e2,
                       bf16x8* __restrict__ Bh, float4* __restrict__ P4) {
    int gid = blockIdx.x * 256 + threadIdx.x;
    if (gid < 4096) {
        int tn = gid >> 7, rem = gid & 127;
        int chunk = (rem >> 6) & 1, q = (rem >> 4) & 3, i = rem & 15;
        int code = tn * 16 + i;
        const float* src = emb + code * DDIM + chunk * 32 + q * 8;
        bf16x8 h;
        #pragma unroll
        for (int j = 0; j < 8; ++j) h[j] = f2bf(src[j]);
        Bh[gid] = h;
    } else if (gid < 4608) {
        int k = gid - 4096;
        const float* row = emb + k * DDIM;
        float r[8];
        #pragma unroll
        for (int j = 0; j < 8; ++j) { float v = row[j]; r[j] = rnd(v * v); }
        #pragma unroll
        for (int m = 1; m < 8; ++m)
            #pragma unroll
            for (int j = 0; j < 8; ++j) { float v = row[8 * m + j]; r[j] += rnd(v * v); }
        e2[k] = ((r[0] + r[1]) + (r[2] + r[3])) + ((r[4] + r[5]) + (r[6] + r[7]));
    } else if (gid < 12800) {
        int pid = gid - 4608;            // 8192 entries
        int kk = pid >> 10, c4 = (pid >> 6) & 15, lane = pid & 63;
        int code = lane * 8 + kk;
        P4[pid] = *(const float4*)(emb + code * DDIM + c4 * 4);
    }
}

// -------------------- fused distance/argmin + epilogue kernel --------------------
// 64 px/block, 4 waves x 16 px. Grid 1024, ~31 KB LDS -> 5 blocks/CU, all resident.
// B staged in 8KB eighths, double-buffered via register prefetch: loads for e+1
// issue before e's barrier, ds_writes hit the opposite buffer -> 1 barrier/eighth,
// global latency fully overlapped.  (R9: quarter restage w/ 2 barriers = 44.5 us,
// 28% occ.)
#define ROWW 40   // u32 stride per px row (16B-aligned frags, modest bank spread)
__global__ __launch_bounds__(256, 5) void k_dist(
        const float* __restrict__ z_e, const float* __restrict__ emb,
        const bf16x8* __restrict__ Bh, const float* __restrict__ e2g,
        int* __restrict__ idx, int* __restrict__ glist, int* __restrict__ nflag,
        int* __restrict__ counts, float* __restrict__ slots,
        float* __restrict__ out) {
    __shared__ unsigned AhU[64 * ROWW];    // 10 KB
    __shared__ bf16x8 Bs[2][512];          // 2 x 8 KB: eighth of codebook, frag order
    __shared__ float e2s[512];
    __shared__ int   hist[512];
    __shared__ int   flist[64];
    __shared__ int   fcnt, fbase;

    int t = threadIdx.x;
    int pxbase = blockIdx.x * 64;
    int batch = pxbase >> 12;
    int p0 = pxbase & 4095;
    const float* zb = z_e + (size_t)batch * (CH * HW) + p0;

    hist[t] = 0; hist[t + 256] = 0;
    e2s[t] = e2g[t]; e2s[t + 256] = e2g[t + 256];
    if (t == 0) fcnt = 0;

    // stage A: 64px x 64ch -> bf16, 2 ch packed per u32. Coalesced loads.
    #pragma unroll
    for (int it = 0; it < 8; ++it) {
        int i = it * 256 + t;            // 0..2047 channel-pair x px
        int cp = i >> 6;                 // channel pair 0..31
        int pp = i & 63;                 // px
        float v0 = zb[(2 * cp) * HW + pp];
        float v1 = zb[(2 * cp + 1) * HW + pp];
        AhU[pp * ROWW + cp] = (unsigned)(unsigned short)f2bf(v0)
                            | ((unsigned)(unsigned short)f2bf(v1) << 16);
    }
    // prefetch eighth 0 of B into registers while A-staging drains
    bf16x8 r0 = Bh[t], r1 = Bh[256 + t];
    __syncthreads();

    int w = t >> 6, lane = t & 63, col = lane & 15, quad = lane >> 4;

    // A fragments: wave w owns px m = w*16 + col; k = chunk*32 + quad*8 + j
    const short* Ahs = (const short*)AhU;
    int m = w * 16 + col;
    bf16x8 a0 = *(const bf16x8*)(Ahs + m * (2 * ROWW) + quad * 8);
    bf16x8 a1 = *(const bf16x8*)(Ahs + m * (2 * ROWW) + 32 + quad * 8);

    float m1[4], m2[4];
    int   i1[4];
    #pragma unroll
    for (int r = 0; r < 4; ++r) { m1[r] = 1e30f; m2[r] = 1e30f; i1[r] = 0; }

    // N loop over 8 codebook eighths, double-buffered (1 barrier per eighth).
    // Safety: iter e computes from Bs[e&1]; iter e+1 writes Bs[(e+1)&1] (disjoint);
    // a wave can only reach iter e+2's writes after the e+1 barrier, which the
    // slowest wave can't pass before finishing iter e's reads.
    for (int e = 0; e < 8; ++e) {
        int buf = e & 1;
        Bs[buf][t] = r0; Bs[buf][256 + t] = r1;
        if (e < 7) { r0 = Bh[(e + 1) * 512 + t]; r1 = Bh[(e + 1) * 512 + 256 + t]; }
        __syncthreads();
        #pragma unroll
        for (int tn4 = 0; tn4 < 4; ++tn4) {
            int tn = e * 4 + tn4;
            bf16x8 c0 = Bs[buf][tn4 * 128 + lane];
            bf16x8 c1 = Bs[buf][tn4 * 128 + 64 + lane];
            float e2v = e2s[tn * 16 + col];
            int n = tn * 16 + col;
            f32x4 acc = {0.f, 0.f, 0.f, 0.f};
            acc = __builtin_amdgcn_mfma_f32_16x16x32_bf16(a0, c0, acc, 0, 0, 0);
            acc = __builtin_amdgcn_mfma_f32_16x16x32_bf16(a1, c1, acc, 0, 0, 0);
            #pragma unroll
            for (int r = 0; r < 4; ++r) {
                float d = fmaf(-2.0f, acc[r], e2v);
                if (d < m1[r])      { m2[r] = m1[r]; m1[r] = d; i1[r] = n; }
                else if (d < m2[r]) { m2[r] = d; }
            }
        }
    }

    // merge the 16 cols (xor butterfly -> every lane holds result for px quad*4+r)
    #pragma unroll
    for (int off = 1; off < 16; off <<= 1) {
        #pragma unroll
        for (int r = 0; r < 4; ++r) {
            float om1 = __shfl_xor(m1[r], off);
            float om2 = __shfl_xor(m2[r], off);
            int   oi  = __shfl_xor(i1[r], off);
            if (om1 < m1[r] || (om1 == m1[r] && oi < i1[r])) {
                m2[r] = fminf(m1[r], om2);
                m1[r] = om1;
                i1[r] = oi;
            } else {
                m2[r] = fminf(m2[r], om1);
            }
        }
    }

    // per-pixel outputs: idx, out-idx, LDS histogram + LDS flag list (no global atomics)
    if (col == 0) {
        #pragma unroll
        for (int r = 0; r < 4; ++r) {
            int g = pxbase + w * 16 + quad * 4 + r;
            idx[g] = i1[r];
            out[OUT_IDX + g] = (float)i1[r];
            atomicAdd(&hist[i1[r]], 1);
            if (m2[r] - m1[r] < MARGIN) {
                int pos = atomicAdd(&fcnt, 1);   // LDS atomic
                flist[pos] = g;
            }
        }
    }

    // fused epilogue: z_q_st for this wave's 16 px (z_e is L1-hot), + loss partial
    int q4 = lane & 3;
    int bidx[4];
    #pragma unroll
    for (int j = 0; j < 4; ++j) bidx[j] = __shfl(i1[j], q4 << 4);  // best for px q4*4+j
    const float* zw = zb + w * 16;
    float* ow = out + (size_t)batch * (CH * HW) + p0 + w * 16;
    float lsum = 0.0f;
    #pragma unroll
    for (int it = 0; it < 4; ++it) {
        int c = it * 16 + (lane >> 2);
        float4 ze = *(const float4*)(zw + c * HW + q4 * 4);
        float d0 = emb[bidx[0] * DDIM + c] - ze.x;
        float d1 = emb[bidx[1] * DDIM + c] - ze.y;
        float d2 = emb[bidx[2] * DDIM + c] - ze.z;
        float d3 = emb[bidx[3] * DDIM + c] - ze.w;
        float4 o = {ze.x + d0, ze.y + d1, ze.z + d2, ze.w + d3};
        *(float4*)(ow + c * HW + q4 * 4) = o;
        lsum = lsum + d0 * d0 + d1 * d1 + d2 * d2 + d3 * d3;
    }
    #pragma unroll
    for (int off = 32; off; off >>= 1) lsum += __shfl_down(lsum, off);
    if (lane == 0) atomicAdd(&slots[((blockIdx.x * 4 + w) & 63) * 16], lsum);

    // flush histogram + flag list (one returning atomic per block)
    __syncthreads();
    int v0 = hist[t];       if (v0) atomicAdd(&counts[t], v0);
    int v1 = hist[t + 256]; if (v1) atomicAdd(&counts[t + 256], v1);
    if (t == 0) fbase = atomicAdd(nflag, fcnt);
    __syncthreads();
    if (t < fcnt) glist[fbase + t] = flist[t];
}

// -------------------- refine: LDS-staged codebook, numpy-fp32-exact re-argmin ------
// R8 lesson: per-pixel global codebook loads serialize at ~400-900 cyc each under
// VGPR pressure -> 50+ us. fp32 codebook staged in LDS quarters; x-vectors in LDS;
// dot loop is pure ds_read + fp64 FMA.  (R9-verified, absmax 0 — unchanged.)
__global__ __launch_bounds__(256) void k_refine(
        const float* __restrict__ z_e, const float* __restrict__ emb,
        const float* __restrict__ e2, const float4* __restrict__ P4,
        const int* __restrict__ glist, const int* __restrict__ nflag,
        int* __restrict__ idx, int* __restrict__ counts,
        float* __restrict__ slots, float* __restrict__ out) {
    __shared__ float4 Ps[2048];      // 32 KB: quarter of transposed codebook
    __shared__ float  xs[32][64];    // 8 KB: 8 flag slots per wave

    int t = threadIdx.x;
    int w = t >> 6, lane = t & 63;
    int wid = blockIdx.x * 4 + w;
    int n = nflag[0];
    if (blockIdx.x * 4 >= n) return;           // block-uniform early exit

    // per-lane e2 for codes lane*8..+7 (coalesced float4 pair)
    float4 ea = ((const float4*)e2)[lane * 2];
    float4 eb = ((const float4*)e2)[lane * 2 + 1];
    float e2v[8] = {ea.x, ea.y, ea.z, ea.w, eb.x, eb.y, eb.z, eb.w};

    for (int s = 0; s * 8192 + blockIdx.x * 4 < n; ++s) {   // block-uniform
        // gather this wave's flags (<=8), stage x-vectors into LDS
        int gidx[8];
        int nf = 0;
        #pragma unroll
        for (int f = 0; f < 8; ++f) {
            int j = s * 8192 + f * 1024 + wid;
            if (j < n) {
                int g = glist[j];                 // wave-uniform scalar load
                gidx[nf] = g;
                int b = g >> 12, p = g & 4095;
                xs[w * 8 + nf][lane] = z_e[(size_t)b * (CH * HW) + (size_t)lane * HW + p];
                ++nf;
            }
        }
        __threadfence_block();

        // numpy pairwise ||x||^2 per flag (broadcast LDS reads)
        float x2f[8];
        for (int f = 0; f < nf; ++f) {
            const float* xr = xs[w * 8 + f];
            float r[8];
            #pragma unroll
            for (int j = 0; j < 8; ++j) { float v = xr[j]; r[j] = rnd(v * v); }
            #pragma unroll
            for (int mm = 1; mm < 8; ++mm)
                #pragma unroll
                for (int j = 0; j < 8; ++j) { float v = xr[8 * mm + j]; r[j] += rnd(v * v); }
            x2f[f] = ((r[0] + r[1]) + (r[2] + r[3])) + ((r[4] + r[5]) + (r[6] + r[7]));
        }

        float bestd[8];
        int   besti[8];
        #pragma unroll
        for (int f = 0; f < 8; ++f) { bestd[f] = INFINITY; besti[f] = 1 << 30; }

        // 4 codebook quarters staged in LDS; lane's codes = lane*8 + (qtr*2+kk2)
        for (int qtr = 0; qtr < 4; ++qtr) {
            __syncthreads();
            #pragma unroll
            for (int it = 0; it < 8; ++it) Ps[it * 256 + t] = P4[qtr * 2048 + it * 256 + t];
            __syncthreads();
            for (int f = 0; f < nf; ++f) {
                const float* xr = xs[w * 8 + f];
                #pragma unroll
                for (int kk2 = 0; kk2 < 2; ++kk2) {
                    double d0 = 0.0, d1 = 0.0, d2 = 0.0, d3 = 0.0;
                    #pragma unroll
                    for (int c4 = 0; c4 < 16; ++c4) {
                        float4 xq = *(const float4*)&xr[c4 * 4];         // broadcast
                        float4 ev = Ps[(kk2 * 16 + c4) * 64 + lane];     // per-lane
                        d0 = fma((double)xq.x, (double)ev.x, d0);
                        d1 = fma((double)xq.y, (double)ev.y, d1);
                        d2 = fma((double)xq.z, (double)ev.z, d2);
                        d3 = fma((double)xq.w, (double)ev.w, d3);
                    }
                    int kk = qtr * 2 + kk2;
                    float dotf = (float)((d0 + d1) + (d2 + d3));  // ~= sgemm dot
                    float tt = x2f[f] + e2v[kk];                  // np fp32 add
                    float d = tt - 2.0f * dotf;                   // np fp32 sub
                    if (d < bestd[f]) { bestd[f] = d; besti[f] = lane * 8 + kk; }
                }
            }
        }

        // reduce per flag (tie -> smaller index = np first occurrence) and patch
        for (int f = 0; f < nf; ++f) {
            float bd = bestd[f];
            int   bi = besti[f];
            #pragma unroll
            for (int off = 32; off; off >>= 1) {
                float od = __shfl_down(bd, off);
                int   oi = __shfl_down(bi, off);
                if (od < bd || (od == bd && oi < bi)) { bd = od; bi = oi; }
            }
            bi = __shfl(bi, 0);
            int g = gidx[f];
            int old = idx[g];
            if (bi != old) {
                int b = g >> 12, p = g & 4095;
                float xc = xs[w * 8 + f][lane];
                float qn = emb[bi * DDIM + lane];
                float qo = emb[old * DDIM + lane];
                float dn = qn - xc, dold = qo - xc;
                out[(size_t)b * (CH * HW) + (size_t)lane * HW + p] = xc + dn;
                float delta = dn * dn - dold * dold;
                #pragma unroll
                for (int off = 32; off; off >>= 1) delta += __shfl_down(delta, off);
                if (lane == 0) {
                    atomicAdd(&slots[(wid & 63) * 16], delta);
                    atomicAdd(&counts[old], -1);
                    atomicAdd(&counts[bi], 1);
                    idx[g] = bi;
                    out[OUT_IDX + g] = (float)bi;
                }
            }
        }
    }
}

// -------------------- final scalars: loss, perplexity --------------------
__global__ void k_final(const int* __restrict__ counts,
                        const float* __restrict__ slots,
                        float* __restrict__ out) {
    int t = threadIdx.x;  // 512 threads, 1 block
    float cnt = (float)counts[t];
    float pb = cnt * (1.0f / 65536.0f);
    float term = pb * logf(pb + 1e-10f);
    #pragma unroll
    for (int off = 32; off; off >>= 1) term += __shfl_down(term, off);
    __shared__ float ls[8];
    __shared__ float lsum;
    int lane = t & 63, w = t >> 6;
    if (lane == 0) ls[w] = term;
    if (w == 0) {                               // wave 0 reduces the 64 loss slots
        float s2 = slots[lane * 16];
        #pragma unroll
        for (int off = 32; off; off >>= 1) s2 += __shfl_down(s2, off);
        if (lane == 0) lsum = s2;
    }
    __syncthreads();
    if (t == 0) {
        float s = 0.0f;
        #pragma unroll
        for (int i = 0; i < 8; ++i) s += ls[i];
        out[OUT_PPL]  = expf(-s);
        out[OUT_LOSS] = 0.25f * (lsum / (float)NELEM);
    }
}

extern "C" void kernel_launch(void* const* d_in, const int* in_sizes, int n_in,
                              void* d_out, int out_size, void* d_ws, size_t ws_size,
                              hipStream_t stream) {
    const float* z_e = (const float*)d_in[0];
    const float* emb = (const float*)d_in[1];
    float* out = (float*)d_out;
    char* ws = (char*)d_ws;

    // ws layout
    int*    idx    = (int*)(ws);              // 65536 ints   [0, 262144)
    int*    glist  = (int*)(ws + 262144);     // 65536 ints   [262144, 524288)
    float*  e2     = (float*)(ws + 524288);   // 512 floats   [524288, 526336)
    int*    nflag  = (int*)(ws + 526336);     // 1 int (+pad) [526336, 526400)
    int*    counts = (int*)(ws + 526400);     // 512 ints     [526400, 528448)
    float*  slots  = (float*)(ws + 528448);   // 64 x 16 floats [528448, 532544)
    bf16x8* Bh     = (bf16x8*)(ws + 532544);  // 4096 x 16 B = 64 KB
    float4* P4     = (float4*)(ws + 598080);  // 8192 x 16 B = 128 KB [598080, 729152)

    // zero nflag + counts + slots (ws is poisoned 0xAA before every timed launch)
    hipMemsetAsync(ws + 526336, 0, 532544 - 526336, stream);

    k_prep<<<50, 256, 0, stream>>>(emb, e2, Bh, P4);
    k_dist<<<NPIX / 64, 256, 0, stream>>>(z_e, emb, Bh, e2, idx, glist, nflag, counts, slots, out);
    k_refine<<<256, 256, 0, stream>>>(z_e, emb, e2, P4, glist, nflag, idx, counts, slots, out);
    k_final<<<1, 512, 0, stream>>>(counts, slots, out);
}

// Round 11
// 139.571 us; speedup vs baseline: 1.1911x; 1.0647x over previous
//
#include <hip/hip_runtime.h>

// Problem constants
#define BATCH 16
#define CH 64          // EMBEDDING_DIM
#define HW 4096        // 64*64
#define NPIX 65536     // BATCH*HW
#define KCODES 512
#define DDIM 64
#define NELEM 4194304  // NPIX*CH

// d_out layout (float32): [z_q_st: NELEM][loss: 1][ppl: 1][indices: NPIX]
#define OUT_LOSS 4194304
#define OUT_PPL  4194305
#define OUT_IDX  4194306

// bf16 gap-error: rms ~4e-5 => 2.2e-4 is ~5.5 sigma; covers np fp32 quantization (7.6e-6)
#define MARGIN 2.2e-4f

typedef short bf16x8 __attribute__((ext_vector_type(8)));
typedef float f32x4  __attribute__((ext_vector_type(4)));

__device__ __forceinline__ float rnd(float s) {   // block fp-contract (numpy-exact squares)
    asm volatile("" : "+v"(s));
    return s;
}
__device__ __forceinline__ short f2bf(float f) {  // RNE fp32->bf16
    unsigned u = __builtin_bit_cast(unsigned, f);
    unsigned r = (u + 0x7fffu + ((u >> 16) & 1u)) >> 16;
    return (short)r;
}

// -------------------- prep: e2 + fragment-ordered bf16 codebook + coalesced fp32 transpose ---
// Bh packing: entry = tn*128 + chunk*64 + lane, lane=(q<<4)|i:
//   code = tn*16+i, k = chunk*32 + q*8 + j (j=0..7), 16B/entry.  (layout HW-verified R4)
// P4 packing (for refine): P4[(kk*16+c4)*64 + lane] = emb[lane*8+kk][c4*4..+3]
__global__ void k_prep(const float* __restrict__ emb, float* __restrict__ e2,
                       bf16x8* __restrict__ Bh, float4* __restrict__ P4) {
    int gid = blockIdx.x * 256 + threadIdx.x;
    if (gid < 4096) {
        int tn = gid >> 7, rem = gid & 127;
        int chunk = (rem >> 6) & 1, q = (rem >> 4) & 3, i = rem & 15;
        int code = tn * 16 + i;
        const float* src = emb + code * DDIM + chunk * 32 + q * 8;
        bf16x8 h;
        #pragma unroll
        for (int j = 0; j < 8; ++j) h[j] = f2bf(src[j]);
        Bh[gid] = h;
    } else if (gid < 4608) {
        int k = gid - 4096;
        const float* row = emb + k * DDIM;
        float r[8];
        #pragma unroll
        for (int j = 0; j < 8; ++j) { float v = row[j]; r[j] = rnd(v * v); }
        #pragma unroll
        for (int m = 1; m < 8; ++m)
            #pragma unroll
            for (int j = 0; j < 8; ++j) { float v = row[8 * m + j]; r[j] += rnd(v * v); }
        e2[k] = ((r[0] + r[1]) + (r[2] + r[3])) + ((r[4] + r[5]) + (r[6] + r[7]));
    } else if (gid < 12800) {
        int pid = gid - 4608;            // 8192 entries
        int kk = pid >> 10, c4 = (pid >> 6) & 15, lane = pid & 63;
        int code = lane * 8 + kk;
        P4[pid] = *(const float4*)(emb + code * DDIM + c4 * 4);
    }
}

// -------------------- fused distance/argmin + epilogue kernel --------------------
// 512 thr = 8 waves x 16 px = 128 px/block. Grid 512 -> 2 blocks/CU, all resident.
// Full 64 KB bf16 codebook staged into LDS ONCE; A-frags loaded direct to regs.
// TWO barriers total per block (R10 had 9; each s_barrier is a full vmcnt drain —
// the structural stall per m99-m141).  LDS ~68.5 KB -> 2 blocks/CU.
__global__ __launch_bounds__(512, 4) void k_dist(
        const float* __restrict__ z_e, const float* __restrict__ emb,
        const bf16x8* __restrict__ Bh, const float* __restrict__ e2g,
        int* __restrict__ idx, int* __restrict__ glist, int* __restrict__ nflag,
        int* __restrict__ counts, float* __restrict__ slots,
        float* __restrict__ out) {
    __shared__ bf16x8 Bs[4096];      // 64 KB: full codebook, fragment order
    __shared__ float e2s[512];
    __shared__ int   hist[512];
    __shared__ int   flist[128];
    __shared__ int   fcnt, fbase;

    int t = threadIdx.x;
    int pxbase = blockIdx.x * 128;
    int batch = pxbase >> 12;
    int p0 = pxbase & 4095;
    const float* zb = z_e + (size_t)batch * (CH * HW) + p0;

    // issue the 8 B-stage loads first so they're in flight during A-loads
    bf16x8 rb[8];
    #pragma unroll
    for (int i = 0; i < 8; ++i) rb[i] = Bh[i * 512 + t];

    hist[t] = 0;
    e2s[t] = e2g[t];
    if (t == 0) fcnt = 0;

    int w = t >> 6, lane = t & 63, col = lane & 15, quad = lane >> 4;
    int px = w * 16 + col;

    // A-frags direct from global: px = w*16+col, k = chunk*32 + quad*8 + j
    bf16x8 a0, a1;
    #pragma unroll
    for (int j = 0; j < 8; ++j) {
        a0[j] = f2bf(zb[(quad * 8 + j) * HW + px]);
        a1[j] = f2bf(zb[(32 + quad * 8 + j) * HW + px]);
    }

    // commit B to LDS; barrier #1
    #pragma unroll
    for (int i = 0; i < 8; ++i) Bs[i * 512 + t] = rb[i];
    __syncthreads();

    float m1[4], m2[4];
    int   i1[4];
    #pragma unroll
    for (int r = 0; r < 4; ++r) { m1[r] = 1e30f; m2[r] = 1e30f; i1[r] = 0; }

    // barrier-free N loop: pure ds_read_b128 + MFMA + select
    #pragma unroll 4
    for (int tn = 0; tn < 32; ++tn) {
        bf16x8 c0 = Bs[tn * 128 + lane];
        bf16x8 c1 = Bs[tn * 128 + 64 + lane];
        float e2v = e2s[tn * 16 + col];
        int n = tn * 16 + col;
        f32x4 acc = {0.f, 0.f, 0.f, 0.f};
        acc = __builtin_amdgcn_mfma_f32_16x16x32_bf16(a0, c0, acc, 0, 0, 0);
        acc = __builtin_amdgcn_mfma_f32_16x16x32_bf16(a1, c1, acc, 0, 0, 0);
        #pragma unroll
        for (int r = 0; r < 4; ++r) {
            float d = fmaf(-2.0f, acc[r], e2v);
            if (d < m1[r])      { m2[r] = m1[r]; m1[r] = d; i1[r] = n; }
            else if (d < m2[r]) { m2[r] = d; }
        }
    }

    // merge the 16 cols (xor butterfly -> every lane holds result for px quad*4+r)
    #pragma unroll
    for (int off = 1; off < 16; off <<= 1) {
        #pragma unroll
        for (int r = 0; r < 4; ++r) {
            float om1 = __shfl_xor(m1[r], off);
            float om2 = __shfl_xor(m2[r], off);
            int   oi  = __shfl_xor(i1[r], off);
            if (om1 < m1[r] || (om1 == m1[r] && oi < i1[r])) {
                m2[r] = fminf(m1[r], om2);
                m1[r] = om1;
                i1[r] = oi;
            } else {
                m2[r] = fminf(m2[r], om1);
            }
        }
    }

    // per-pixel outputs: idx, out-idx, LDS histogram + LDS flag list (no global atomics)
    if (col == 0) {
        #pragma unroll
        for (int r = 0; r < 4; ++r) {
            int g = pxbase + w * 16 + quad * 4 + r;
            idx[g] = i1[r];
            out[OUT_IDX + g] = (float)i1[r];
            atomicAdd(&hist[i1[r]], 1);
            if (m2[r] - m1[r] < MARGIN) {
                int pos = atomicAdd(&fcnt, 1);   // LDS atomic
                flist[pos] = g;
            }
        }
    }

    // fused epilogue: z_q_st for this wave's 16 px (z_e is L1/L3-hot), + loss partial
    int q4 = lane & 3;
    int bidx[4];
    #pragma unroll
    for (int j = 0; j < 4; ++j) bidx[j] = __shfl(i1[j], q4 << 4);  // best for px q4*4+j
    const float* zw = zb + w * 16;
    float* ow = out + (size_t)batch * (CH * HW) + p0 + w * 16;
    float lsum = 0.0f;
    #pragma unroll
    for (int it = 0; it < 4; ++it) {
        int c = it * 16 + (lane >> 2);
        float4 ze = *(const float4*)(zw + c * HW + q4 * 4);
        float d0 = emb[bidx[0] * DDIM + c] - ze.x;
        float d1 = emb[bidx[1] * DDIM + c] - ze.y;
        float d2 = emb[bidx[2] * DDIM + c] - ze.z;
        float d3 = emb[bidx[3] * DDIM + c] - ze.w;
        float4 o = {ze.x + d0, ze.y + d1, ze.z + d2, ze.w + d3};
        *(float4*)(ow + c * HW + q4 * 4) = o;
        lsum = lsum + d0 * d0 + d1 * d1 + d2 * d2 + d3 * d3;
    }
    #pragma unroll
    for (int off = 32; off; off >>= 1) lsum += __shfl_down(lsum, off);
    if (lane == 0) atomicAdd(&slots[((blockIdx.x * 8 + w) & 63) * 16], lsum);

    // barrier #2, then flush histogram + flag list (one returning atomic per block)
    __syncthreads();
    int v0 = hist[t];
    if (v0) atomicAdd(&counts[t], v0);
    if (t == 0) fbase = atomicAdd(nflag, fcnt);
    __syncthreads();
    if (t < fcnt) glist[fbase + t] = flist[t];
}

// -------------------- refine: full codebook in LDS, numpy-fp32-exact re-argmin ------
// Full 128 KB fp32 transposed codebook staged ONCE (1 block/CU), one barrier, then
// each wave grid-strides flags with no further barriers. Numerics identical to the
// R9/R10-verified path.  __launch_bounds__(256) is LOAD-BEARING (R5: VGPR cap 64
// -> spill -> 90 MB scratch traffic).
__global__ __launch_bounds__(256) void k_refine(
        const float* __restrict__ z_e, const float* __restrict__ emb,
        const float* __restrict__ e2, const float4* __restrict__ P4,
        const int* __restrict__ glist, const int* __restrict__ nflag,
        int* __restrict__ idx, int* __restrict__ counts,
        float* __restrict__ slots, float* __restrict__ out) {
    __shared__ float4 Ps[8192];      // 128 KB: full transposed codebook
    __shared__ float  xs[4][64];     // one x-vector slot per wave

    int t = threadIdx.x;
    int w = t >> 6, lane = t & 63;
    int n = nflag[0];
    if (blockIdx.x >= n) return;     // block-uniform early exit (handles n==0)

    #pragma unroll
    for (int i = 0; i < 32; ++i) Ps[i * 256 + t] = P4[i * 256 + t];
    __syncthreads();                 // the only barrier

    // per-lane e2 for codes lane*8..+7 (coalesced float4 pair)
    float4 ea = ((const float4*)e2)[lane * 2];
    float4 eb = ((const float4*)e2)[lane * 2 + 1];
    float e2v[8] = {ea.x, ea.y, ea.z, ea.w, eb.x, eb.y, eb.z, eb.w};

    int wid = blockIdx.x * 4 + w;
    for (int j = wid; j < n; j += 1024) {
        int g = glist[j];                 // wave-uniform scalar load
        int b = g >> 12, p = g & 4095;
        xs[w][lane] = z_e[(size_t)b * (CH * HW) + (size_t)lane * HW + p];
        __threadfence_block();            // wave-lockstep LDS visibility

        const float* xr = xs[w];
        // numpy pairwise ||x||^2 (8 accumulators + tree), broadcast LDS reads
        float r[8];
        #pragma unroll
        for (int jj = 0; jj < 8; ++jj) { float v = xr[jj]; r[jj] = rnd(v * v); }
        #pragma unroll
        for (int mm = 1; mm < 8; ++mm)
            #pragma unroll
            for (int jj = 0; jj < 8; ++jj) { float v = xr[8 * mm + jj]; r[jj] += rnd(v * v); }
        float x2 = ((r[0] + r[1]) + (r[2] + r[3])) + ((r[4] + r[5]) + (r[6] + r[7]));

        float bestd = INFINITY;
        int besti = 1 << 30;
        #pragma unroll
        for (int kk = 0; kk < 8; ++kk) {
            double d0 = 0.0, d1 = 0.0, d2 = 0.0, d3 = 0.0;
            #pragma unroll
            for (int c4 = 0; c4 < 16; ++c4) {
                float4 xq = *(const float4*)&xr[c4 * 4];         // broadcast
                float4 ev = Ps[(kk * 16 + c4) * 64 + lane];      // per-lane, conflict-free
                d0 = fma((double)xq.x, (double)ev.x, d0);
                d1 = fma((double)xq.y, (double)ev.y, d1);
                d2 = fma((double)xq.z, (double)ev.z, d2);
                d3 = fma((double)xq.w, (double)ev.w, d3);
            }
            float dotf = (float)((d0 + d1) + (d2 + d3));  // ~= sgemm dot
            float tt = x2 + e2v[kk];                      // np fp32 add
            float d = tt - 2.0f * dotf;                   // np fp32 sub
            if (d < bestd) { bestd = d; besti = lane * 8 + kk; }
        }
        #pragma unroll
        for (int off = 32; off; off >>= 1) {
            float od = __shfl_down(bestd, off);
            int   oi = __shfl_down(besti, off);
            if (od < bestd || (od == bestd && oi < besti)) { bestd = od; besti = oi; }
        }
        besti = __shfl(besti, 0);

        int old = idx[g];
        if (besti != old) {
            // patch z_q_st row (lane c = channel c), loss delta, counts, index
            float xc = xr[lane];
            float qn = emb[besti * DDIM + lane];
            float qo = emb[old * DDIM + lane];
            float dn = qn - xc, dold = qo - xc;
            out[(size_t)b * (CH * HW) + (size_t)lane * HW + p] = xc + dn;
            float delta = dn * dn - dold * dold;
            #pragma unroll
            for (int off = 32; off; off >>= 1) delta += __shfl_down(delta, off);
            if (lane == 0) {
                atomicAdd(&slots[(wid & 63) * 16], delta);
                atomicAdd(&counts[old], -1);
                atomicAdd(&counts[besti], 1);
                idx[g] = besti;
                out[OUT_IDX + g] = (float)besti;
            }
        }
    }
}

// -------------------- final scalars: loss, perplexity --------------------
__global__ void k_final(const int* __restrict__ counts,
                        const float* __restrict__ slots,
                        float* __restrict__ out) {
    int t = threadIdx.x;  // 512 threads, 1 block
    float cnt = (float)counts[t];
    float pb = cnt * (1.0f / 65536.0f);
    float term = pb * logf(pb + 1e-10f);
    #pragma unroll
    for (int off = 32; off; off >>= 1) term += __shfl_down(term, off);
    __shared__ float ls[8];
    __shared__ float lsum;
    int lane = t & 63, w = t >> 6;
    if (lane == 0) ls[w] = term;
    if (w == 0) {                               // wave 0 reduces the 64 loss slots
        float s2 = slots[lane * 16];
        #pragma unroll
        for (int off = 32; off; off >>= 1) s2 += __shfl_down(s2, off);
        if (lane == 0) lsum = s2;
    }
    __syncthreads();
    if (t == 0) {
        float s = 0.0f;
        #pragma unroll
        for (int i = 0; i < 8; ++i) s += ls[i];
        out[OUT_PPL]  = expf(-s);
        out[OUT_LOSS] = 0.25f * (lsum / (float)NELEM);
    }
}

extern "C" void kernel_launch(void* const* d_in, const int* in_sizes, int n_in,
                              void* d_out, int out_size, void* d_ws, size_t ws_size,
                              hipStream_t stream) {
    const float* z_e = (const float*)d_in[0];
    const float* emb = (const float*)d_in[1];
    float* out = (float*)d_out;
    char* ws = (char*)d_ws;

    // ws layout
    int*    idx    = (int*)(ws);              // 65536 ints   [0, 262144)
    int*    glist  = (int*)(ws + 262144);     // 65536 ints   [262144, 524288)
    float*  e2     = (float*)(ws + 524288);   // 512 floats   [524288, 526336)
    int*    nflag  = (int*)(ws + 526336);     // 1 int (+pad) [526336, 526400)
    int*    counts = (int*)(ws + 526400);     // 512 ints     [526400, 528448)
    float*  slots  = (float*)(ws + 528448);   // 64 x 16 floats [528448, 532544)
    bf16x8* Bh     = (bf16x8*)(ws + 532544);  // 4096 x 16 B = 64 KB
    float4* P4     = (float4*)(ws + 598080);  // 8192 x 16 B = 128 KB [598080, 729152)

    // zero nflag + counts + slots (ws is poisoned 0xAA before every timed launch)
    hipMemsetAsync(ws + 526336, 0, 532544 - 526336, stream);

    k_prep<<<50, 256, 0, stream>>>(emb, e2, Bh, P4);
    k_dist<<<NPIX / 128, 512, 0, stream>>>(z_e, emb, Bh, e2, idx, glist, nflag, counts, slots, out);
    k_refine<<<256, 256, 0, stream>>>(z_e, emb, e2, P4, glist, nflag, idx, counts, slots, out);
    k_final<<<1, 512, 0, stream>>>(counts, slots, out);
}